// Round 9
// baseline (423.012 us; speedup 1.0000x reference)
//
#include <hip/hip_runtime.h>
#include <math.h>

// VQ-VAE eval forward via MFMA GEMM, monolithic, wave-decoupled.
// inputs: [128,1024,64] fp32, embedding: [512,64] fp32
// out: loss[1] | quantized[8388608] | perplexity[1] | encodings[67108864]
//
// R9: after one staging barrier, each wave owns its 16-row tile end-to-end
// (sweep -> merge -> rescore -> stores) with NO block-wide barriers, so waves
// slide and the store stream smears against compute (R8 convoyed: all blocks
// sweep together with HBM idle, then all store together). Wave-internal
// exchange via wave-private LDS (in-order DS pipe per wave + volatile +
// wave_barrier). Numerics unchanged: hi/lo bf16 6-MFMA + top-2 + exact rescore.

#define NK 512
#define ND 64
#define NROWS 131072
#define ROWS_PB 64
#define BLOCK 256
#define NBLOCKS (NROWS / ROWS_PB)   // 2048
#define NTILES 32
#define XSTRIDE 68                  // lds_x row stride (floats)
#define MARGIN 0.02f

#define Q_OFF    1
#define PERP_OFF 8388609
#define ENC_OFF  8388610

typedef float vf2 __attribute__((ext_vector_type(2)));
typedef float vf4 __attribute__((ext_vector_type(4)));
typedef short vs8 __attribute__((ext_vector_type(8)));

__device__ __forceinline__ unsigned short bf16_rne(float v) {
    union { float f; unsigned int u; } a; a.f = v;
    return (unsigned short)((a.u + 0x7FFFu + ((a.u >> 16) & 1u)) >> 16);
}
__device__ __forceinline__ float bf16_to_f(unsigned short s) {
    union { unsigned int u; float f; } a; a.u = ((unsigned int)s) << 16;
    return a.f;
}

// ---- prep: E -> B-fragment stream (hi/lo bf16) + |e|^2 fp32 ----
__global__ __launch_bounds__(64) void vq_prep(const float* __restrict__ emb,
                                              float* __restrict__ eknorm,
                                              unsigned int* __restrict__ efrag) {
    const int t = blockIdx.x;
    const int l = threadIdx.x;
    const int c = t * 16 + (l & 15);
    const int quad = l >> 4;
    #pragma unroll
    for (int f = 0; f < 4; ++f) {
        const int kbase = (f & 1) * 32 + quad * 8;
        unsigned int w[4];
        #pragma unroll
        for (int d = 0; d < 4; ++d) {
            float v0 = emb[c * ND + kbase + 2 * d];
            float v1 = emb[c * ND + kbase + 2 * d + 1];
            unsigned short h0 = bf16_rne(v0), h1 = bf16_rne(v1);
            unsigned short l0 = bf16_rne(v0 - bf16_to_f(h0));
            unsigned short l1 = bf16_rne(v1 - bf16_to_f(h1));
            unsigned short e0 = (f < 2) ? h0 : l0;
            unsigned short e1 = (f < 2) ? h1 : l1;
            w[d] = (unsigned int)e0 | ((unsigned int)e1 << 16);
        }
        unsigned int* dst = efrag + ((size_t)(t * 4 + f) * 64 + l) * 4;
        dst[0] = w[0]; dst[1] = w[1]; dst[2] = w[2]; dst[3] = w[3];
    }
    if (quad == 0) {
        const vf4* er = (const vf4*)(emb + c * ND);
        float s0 = 0.f, s1 = 0.f, s2 = 0.f, s3 = 0.f;
        #pragma unroll
        for (int j = 0; j < 16; ++j) {
            vf4 v = er[j];
            s0 += v.x * v.x; s1 += v.y * v.y; s2 += v.z * v.z; s3 += v.w * v.w;
        }
        eknorm[c] = (s0 + s1) + (s2 + s3);
    }
}

__global__ __launch_bounds__(BLOCK) void vq_main(const float* __restrict__ x,
                                                 const float* __restrict__ emb,
                                                 const float* __restrict__ eknorm,
                                                 const unsigned int* __restrict__ efrag,
                                                 float* __restrict__ out,
                                                 int* __restrict__ g_counts,
                                                 float* __restrict__ g_loss) {
    __shared__ float lds_x[ROWS_PB * XSTRIDE];
    __shared__ float ek_lds[NK];
    __shared__ float d1w[ROWS_PB], d2w[ROWS_PB];
    __shared__ int   i1w[ROWS_PB], i2w[ROWS_PB];
    __shared__ int   idxw[ROWS_PB];

    const int tid  = threadIdx.x;
    const int wave = tid >> 6;
    const int lane = tid & 63;
    const int col  = lane & 15;
    const int quad = lane >> 4;

    // ---- stage X tile + eknorm into LDS (block-wide, coalesced), ONE barrier ----
    {
        const vf4* xp = (const vf4*)(x + (size_t)blockIdx.x * ROWS_PB * ND);
        #pragma unroll
        for (int i = 0; i < 4; ++i) {
            int e4 = tid + i * BLOCK;
            int r  = e4 >> 4;
            int c4 = (e4 & 15) * 4;
            *(vf4*)&lds_x[r * XSTRIDE + c4] = xp[e4];
        }
        ek_lds[tid] = eknorm[tid];
        ek_lds[tid + 256] = eknorm[tid + 256];
    }
    __syncthreads();   // the ONLY block barrier

    // ---- A-fragments (hi/lo): m = lane&15, k = quad*8 + j ----
    const int arow = wave * 16 + col;
    vs8 ah0, ah1, al0, al1;
    {
        const float* xr = &lds_x[arow * XSTRIDE];
        #pragma unroll
        for (int j = 0; j < 8; ++j) {
            float va = xr[quad * 8 + j];
            float vb = xr[32 + quad * 8 + j];
            unsigned short ha = bf16_rne(va);
            unsigned short hb = bf16_rne(vb);
            ah0[j] = (short)ha; al0[j] = (short)bf16_rne(va - bf16_to_f(ha));
            ah1[j] = (short)hb; al1[j] = (short)bf16_rne(vb - bf16_to_f(hb));
        }
    }

    // ---- sweep 32 code-tiles: 6 MFMA each, top-2 tracking ----
    float d1[4], d2[4];
    int   i1[4], i2[4];
    #pragma unroll
    for (int r = 0; r < 4; ++r) { d1[r] = INFINITY; d2[r] = INFINITY; i1[r] = 0x7FFFFFFF; i2[r] = 0x7FFFFFFF; }

    const vs8* bbase = (const vs8*)efrag;
    vs8 b0 = bbase[0 * 64 + lane];
    vs8 b1 = bbase[1 * 64 + lane];
    vs8 b2 = bbase[2 * 64 + lane];
    vs8 b3 = bbase[3 * 64 + lane];

    for (int t = 0; t < NTILES; ++t) {
        vs8 n0, n1, n2, n3;
        if (t + 1 < NTILES) {
            n0 = bbase[((t + 1) * 4 + 0) * 64 + lane];
            n1 = bbase[((t + 1) * 4 + 1) * 64 + lane];
            n2 = bbase[((t + 1) * 4 + 2) * 64 + lane];
            n3 = bbase[((t + 1) * 4 + 3) * 64 + lane];
        }
        vf4 acc0 = {0.f, 0.f, 0.f, 0.f};
        vf4 acc1 = {0.f, 0.f, 0.f, 0.f};
        acc0 = __builtin_amdgcn_mfma_f32_16x16x32_bf16(ah0, b0, acc0, 0, 0, 0);
        acc1 = __builtin_amdgcn_mfma_f32_16x16x32_bf16(ah1, b1, acc1, 0, 0, 0);
        acc0 = __builtin_amdgcn_mfma_f32_16x16x32_bf16(al0, b0, acc0, 0, 0, 0);
        acc1 = __builtin_amdgcn_mfma_f32_16x16x32_bf16(al1, b1, acc1, 0, 0, 0);
        acc0 = __builtin_amdgcn_mfma_f32_16x16x32_bf16(ah0, b2, acc0, 0, 0, 0);
        acc1 = __builtin_amdgcn_mfma_f32_16x16x32_bf16(ah1, b3, acc1, 0, 0, 0);

        const float ek = ek_lds[t * 16 + col];
        const int cidx = t * 16 + col;
        #pragma unroll
        for (int r = 0; r < 4; ++r) {
            float d = ek - 2.f * (acc0[r] + acc1[r]);
            bool lt1 = d < d1[r];
            bool lt2 = d < d2[r];
            float nd2 = lt1 ? d1[r] : (lt2 ? d : d2[r]);
            int   ni2 = lt1 ? i1[r] : (lt2 ? cidx : i2[r]);
            d2[r] = nd2; i2[r] = ni2;
            d1[r] = lt1 ? d : d1[r];
            i1[r] = lt1 ? cidx : i1[r];
        }
        b0 = n0; b1 = n1; b2 = n2; b3 = n3;
    }

    // ---- butterfly-merge top-2 across the 16 col lanes ----
    #pragma unroll
    for (int m = 8; m >= 1; m >>= 1) {
        #pragma unroll
        for (int r = 0; r < 4; ++r) {
            float od1 = __shfl_xor(d1[r], m);
            int   oi1 = __shfl_xor(i1[r], m);
            float od2 = __shfl_xor(d2[r], m);
            int   oi2 = __shfl_xor(i2[r], m);
            bool aF = (d1[r] < od1) || (d1[r] == od1 && i1[r] < oi1);
            float n1 = aF ? d1[r] : od1;  int ni1 = aF ? i1[r] : oi1;
            float ca = aF ? od1 : d1[r];  int cia = aF ? oi1 : i1[r];
            float cb = aF ? d2[r] : od2;  int cib = aF ? i2[r] : oi2;
            bool bF = (cb < ca) || (cb == ca && cib < cia);
            float n2 = bF ? cb : ca;      int ni2 = bF ? cib : cia;
            d1[r] = n1; i1[r] = ni1; d2[r] = n2; i2[r] = ni2;
        }
    }
    // ---- wave-private exchange (no block sync; DS is in-order per wave) ----
    if (col == 0) {
        #pragma unroll
        for (int r = 0; r < 4; ++r) {
            int lr = wave * 16 + quad * 4 + r;   // C layout: row = quad*4 + reg
            ((volatile float*)d1w)[lr] = d1[r];
            ((volatile int*)  i1w)[lr] = i1[r];
            ((volatile float*)d2w)[lr] = d2[r];
            ((volatile int*)  i2w)[lr] = i2[r];
        }
    }
    __builtin_amdgcn_wave_barrier();

    // ---- lanes 0-15: rescore near-ties exact; commit idx + hist + loss ----
    if (lane < 16) {
        const int lr = wave * 16 + lane;         // row within block
        int   am   = ((volatile int*)  i1w)[lr];
        float dfin = ((volatile float*)d1w)[lr];
        float dsec = ((volatile float*)d2w)[lr];
        if (dsec - dfin < MARGIN) {
            int ia = am, ib = ((volatile int*)i2w)[lr];
            const float* xr = &lds_x[lr * XSTRIDE];
            float da, db;
            {
                const vf4* er = (const vf4*)(emb + ia * ND);
                float s0 = 0.f, s1 = 0.f, s2 = 0.f, s3 = 0.f;
                #pragma unroll
                for (int j = 0; j < 16; ++j) {
                    vf4 v = er[j];
                    s0 += xr[4 * j] * v.x; s1 += xr[4 * j + 1] * v.y;
                    s2 += xr[4 * j + 2] * v.z; s3 += xr[4 * j + 3] * v.w;
                }
                da = ek_lds[ia] - 2.f * ((s0 + s1) + (s2 + s3));
            }
            {
                const vf4* er = (const vf4*)(emb + ib * ND);
                float s0 = 0.f, s1 = 0.f, s2 = 0.f, s3 = 0.f;
                #pragma unroll
                for (int j = 0; j < 16; ++j) {
                    vf4 v = er[j];
                    s0 += xr[4 * j] * v.x; s1 += xr[4 * j + 1] * v.y;
                    s2 += xr[4 * j + 2] * v.z; s3 += xr[4 * j + 3] * v.w;
                }
                db = ek_lds[ib] - 2.f * ((s0 + s1) + (s2 + s3));
            }
            bool useB = (db < da) || (db == da && ib < ia);   // numpy tie-break
            am   = useB ? ib : ia;
            dfin = useB ? db : da;
        }
        ((volatile int*)idxw)[lr] = am;
        atomicAdd(&g_counts[am], 1);

        // loss partial: |x-e|^2 = xnorm + dfin
        float xn;
        {
            const float* xr = &lds_x[lr * XSTRIDE];
            float s0 = 0.f, s1 = 0.f, s2 = 0.f, s3 = 0.f;
            #pragma unroll
            for (int j = 0; j < 16; ++j) {
                s0 += xr[4 * j] * xr[4 * j];         s1 += xr[4 * j + 1] * xr[4 * j + 1];
                s2 += xr[4 * j + 2] * xr[4 * j + 2]; s3 += xr[4 * j + 3] * xr[4 * j + 3];
            }
            xn = (s0 + s1) + (s2 + s3);
        }
        float lossv = xn + dfin;
        #pragma unroll
        for (int off = 8; off >= 1; off >>= 1) lossv += __shfl_down(lossv, off);
        if (lane == 0) atomicAdd(g_loss, lossv);
    }
    __builtin_amdgcn_wave_barrier();

    // ---- encodings: this wave's 16 rows = 8192 floats at base ≡ 8 mod 16.
    //      Layout: vf2 head (row0 c0-1) + 2047 vf4 + vf2 tail (row15 c510-511).
    float* wenc = out + ENC_OFF + (size_t)blockIdx.x * (ROWS_PB * NK) + wave * (16 * NK);
    if (lane == 0) {
        int a0 = ((volatile int*)idxw)[wave * 16];
        vf2 h; h.x = (a0 == 0) ? 1.f : 0.f; h.y = (a0 == 1) ? 1.f : 0.f;
        *(vf2*)wenc = h;
        int a15 = ((volatile int*)idxw)[wave * 16 + 15];
        vf2 tl; tl.x = (a15 == 510) ? 1.f : 0.f; tl.y = (a15 == 511) ? 1.f : 0.f;
        *(vf2*)(wenc + 16 * NK - 2) = tl;
    }
    {
        const bool crossing = (lane == 63);
        #pragma unroll
        for (int i = 0; i < 32; ++i) {
            int j = lane + 64 * i;
            if (j < 2047) {
                int f = 2 + 4 * j;             // float offset in wave slice
                int r = f >> 9;                // row 0..15
                int c0 = f & 511;
                vf4 v;
                if (crossing && (i & 1)) {     // f spans rows r and r+1 (c0==510)
                    int am0 = ((volatile int*)idxw)[wave * 16 + r];
                    int am1 = ((volatile int*)idxw)[wave * 16 + r + 1];
                    v.x = (am0 == 510) ? 1.f : 0.f;
                    v.y = (am0 == 511) ? 1.f : 0.f;
                    v.z = (am1 == 0)   ? 1.f : 0.f;
                    v.w = (am1 == 1)   ? 1.f : 0.f;
                } else {
                    int am = ((volatile int*)idxw)[wave * 16 + r];
                    v.x = (am == c0)     ? 1.f : 0.f;
                    v.y = (am == c0 + 1) ? 1.f : 0.f;
                    v.z = (am == c0 + 2) ? 1.f : 0.f;
                    v.w = (am == c0 + 3) ? 1.f : 0.f;
                }
                *(vf4*)(wenc + f) = v;
            }
        }
    }

    // ---- quantized: this wave's 16 rows, uniform emb row per iter ----
    {
        float* qout = out + Q_OFF + (size_t)blockIdx.x * (ROWS_PB * ND) + wave * (16 * ND);
        #pragma unroll
        for (int i = 0; i < 16; ++i) {
            int am = ((volatile int*)idxw)[wave * 16 + i];
            qout[i * ND + lane] = emb[am * ND + lane];
        }
    }
}

__global__ __launch_bounds__(512) void vq_final(const int* __restrict__ g_counts,
                                                const float* __restrict__ g_loss,
                                                float* __restrict__ out) {
    __shared__ float red[8];
    int t = threadIdx.x;
    float p = (float)g_counts[t] * (1.0f / (float)NROWS);
    float h = p * logf(p + 1e-10f);
    #pragma unroll
    for (int off = 32; off >= 1; off >>= 1) h += __shfl_down(h, off);
    if ((t & 63) == 0) red[t >> 6] = h;
    __syncthreads();
    if (t == 0) {
        float s = 0.f;
        #pragma unroll
        for (int i = 0; i < 8; ++i) s += red[i];
        out[PERP_OFF] = expf(-s);
        out[0] = 0.25f * g_loss[0] / (float)(NROWS * ND);
    }
}

extern "C" void kernel_launch(void* const* d_in, const int* in_sizes, int n_in,
                              void* d_out, int out_size, void* d_ws, size_t ws_size,
                              hipStream_t stream) {
    const float* x   = (const float*)d_in[0];
    const float* emb = (const float*)d_in[1];
    float* out = (float*)d_out;

    int*          g_counts = (int*)d_ws;                           // 512 ints
    float*        g_loss   = (float*)((char*)d_ws + 2048);         // 1 float
    float*        eknorm   = (float*)((char*)d_ws + 4096);         // 512 floats
    unsigned int* efrag    = (unsigned int*)((char*)d_ws + 8192);  // 128 KB

    // ws re-poisoned to 0xAA before every launch — zero counts+loss.
    (void)hipMemsetAsync(d_ws, 0, 4096, stream);

    vq_prep<<<NTILES, 64, 0, stream>>>(emb, eknorm, efrag);
    vq_main<<<NBLOCKS, BLOCK, 0, stream>>>(x, emb, eknorm, efrag, out, g_counts, g_loss);
    vq_final<<<1, 512, 0, stream>>>(g_counts, g_loss, out);
}

// Round 10
// 387.115 us; speedup vs baseline: 1.0927x; 1.0927x over previous
//
#include <hip/hip_runtime.h>
#include <math.h>

// VQ-VAE eval forward via MFMA GEMM, monolithic (R8 structure reverted).
// inputs: [128,1024,64] fp32, embedding: [512,64] fp32
// out: loss[1] | quantized[8388608] | perplexity[1] | encodings[67108864]
//
// R10: R8 (best verified monolith: hi/lo bf16 6-MFMA sweep + top-2 + exact
// rescore, arithmetic one-hot vf4 enc stores, plain stores) + one tweak:
// quantized-gather LOADS issued into registers before the enc store burst,
// stores after — gather latency hides under the 268MB store drain.
// R7 (split kernels) and R9 (wave-decoupled, volatile LDS) both regressed.

#define NK 512
#define ND 64
#define NROWS 131072
#define ROWS_PB 64
#define BLOCK 256
#define NBLOCKS (NROWS / ROWS_PB)   // 2048
#define NTILES 32
#define XSTRIDE 68                  // lds_x row stride (floats)
#define MARGIN 0.02f

#define Q_OFF    1
#define PERP_OFF 8388609
#define ENC_OFF  8388610

typedef float vf2 __attribute__((ext_vector_type(2)));
typedef float vf4 __attribute__((ext_vector_type(4)));
typedef short vs8 __attribute__((ext_vector_type(8)));

__device__ __forceinline__ unsigned short bf16_rne(float v) {
    union { float f; unsigned int u; } a; a.f = v;
    return (unsigned short)((a.u + 0x7FFFu + ((a.u >> 16) & 1u)) >> 16);
}
__device__ __forceinline__ float bf16_to_f(unsigned short s) {
    union { unsigned int u; float f; } a; a.u = ((unsigned int)s) << 16;
    return a.f;
}

// ---- prep: E -> B-fragment stream (hi/lo bf16) + |e|^2 fp32 ----
// B-frag lane map (16x16x32): n = lane&15 (code-in-tile), k = (lane>>4)*8 + j
__global__ __launch_bounds__(64) void vq_prep(const float* __restrict__ emb,
                                              float* __restrict__ eknorm,
                                              unsigned int* __restrict__ efrag) {
    const int t = blockIdx.x;
    const int l = threadIdx.x;
    const int c = t * 16 + (l & 15);
    const int quad = l >> 4;
    #pragma unroll
    for (int f = 0; f < 4; ++f) {
        const int kbase = (f & 1) * 32 + quad * 8;
        unsigned int w[4];
        #pragma unroll
        for (int d = 0; d < 4; ++d) {
            float v0 = emb[c * ND + kbase + 2 * d];
            float v1 = emb[c * ND + kbase + 2 * d + 1];
            unsigned short h0 = bf16_rne(v0), h1 = bf16_rne(v1);
            unsigned short l0 = bf16_rne(v0 - bf16_to_f(h0));
            unsigned short l1 = bf16_rne(v1 - bf16_to_f(h1));
            unsigned short e0 = (f < 2) ? h0 : l0;
            unsigned short e1 = (f < 2) ? h1 : l1;
            w[d] = (unsigned int)e0 | ((unsigned int)e1 << 16);
        }
        unsigned int* dst = efrag + ((size_t)(t * 4 + f) * 64 + l) * 4;
        dst[0] = w[0]; dst[1] = w[1]; dst[2] = w[2]; dst[3] = w[3];
    }
    if (quad == 0) {
        const vf4* er = (const vf4*)(emb + c * ND);
        float s0 = 0.f, s1 = 0.f, s2 = 0.f, s3 = 0.f;
        #pragma unroll
        for (int j = 0; j < 16; ++j) {
            vf4 v = er[j];
            s0 += v.x * v.x; s1 += v.y * v.y; s2 += v.z * v.z; s3 += v.w * v.w;
        }
        eknorm[c] = (s0 + s1) + (s2 + s3);
    }
}

__global__ __launch_bounds__(BLOCK) void vq_main(const float* __restrict__ x,
                                                 const float* __restrict__ emb,
                                                 const float* __restrict__ eknorm,
                                                 const unsigned int* __restrict__ efrag,
                                                 float* __restrict__ out,
                                                 int* __restrict__ g_counts,
                                                 float* __restrict__ g_loss) {
    __shared__ float lds_x[ROWS_PB * XSTRIDE];
    __shared__ float ek_lds[NK];
    __shared__ float d1s[ROWS_PB], d2s[ROWS_PB];
    __shared__ int   i1s[ROWS_PB], i2s[ROWS_PB];
    __shared__ int   idx_s[ROWS_PB];

    const int tid  = threadIdx.x;
    const int wave = tid >> 6;
    const int lane = tid & 63;
    const int col  = lane & 15;
    const int quad = lane >> 4;

    // ---- stage X tile + eknorm into LDS ----
    {
        const vf4* xp = (const vf4*)(x + (size_t)blockIdx.x * ROWS_PB * ND);
        #pragma unroll
        for (int i = 0; i < 4; ++i) {
            int e4 = tid + i * BLOCK;
            int r  = e4 >> 4;
            int c4 = (e4 & 15) * 4;
            *(vf4*)&lds_x[r * XSTRIDE + c4] = xp[e4];
        }
        ek_lds[tid] = eknorm[tid];
        ek_lds[tid + 256] = eknorm[tid + 256];
    }
    __syncthreads();

    // ---- A-fragments (hi/lo): m = lane&15, k = quad*8 + j ----
    const int arow = wave * 16 + col;
    vs8 ah0, ah1, al0, al1;
    {
        const float* xr = &lds_x[arow * XSTRIDE];
        #pragma unroll
        for (int j = 0; j < 8; ++j) {
            float va = xr[quad * 8 + j];
            float vb = xr[32 + quad * 8 + j];
            unsigned short ha = bf16_rne(va);
            unsigned short hb = bf16_rne(vb);
            ah0[j] = (short)ha; al0[j] = (short)bf16_rne(va - bf16_to_f(ha));
            ah1[j] = (short)hb; al1[j] = (short)bf16_rne(vb - bf16_to_f(hb));
        }
    }

    // ---- sweep 32 code-tiles: 6 MFMA each, top-2 tracking ----
    float d1[4], d2[4];
    int   i1[4], i2[4];
    #pragma unroll
    for (int r = 0; r < 4; ++r) { d1[r] = INFINITY; d2[r] = INFINITY; i1[r] = 0x7FFFFFFF; i2[r] = 0x7FFFFFFF; }

    const vs8* bbase = (const vs8*)efrag;
    vs8 b0 = bbase[0 * 64 + lane];
    vs8 b1 = bbase[1 * 64 + lane];
    vs8 b2 = bbase[2 * 64 + lane];
    vs8 b3 = bbase[3 * 64 + lane];

    for (int t = 0; t < NTILES; ++t) {
        vs8 n0, n1, n2, n3;
        if (t + 1 < NTILES) {
            n0 = bbase[((t + 1) * 4 + 0) * 64 + lane];
            n1 = bbase[((t + 1) * 4 + 1) * 64 + lane];
            n2 = bbase[((t + 1) * 4 + 2) * 64 + lane];
            n3 = bbase[((t + 1) * 4 + 3) * 64 + lane];
        }
        vf4 acc0 = {0.f, 0.f, 0.f, 0.f};
        vf4 acc1 = {0.f, 0.f, 0.f, 0.f};
        acc0 = __builtin_amdgcn_mfma_f32_16x16x32_bf16(ah0, b0, acc0, 0, 0, 0);
        acc1 = __builtin_amdgcn_mfma_f32_16x16x32_bf16(ah1, b1, acc1, 0, 0, 0);
        acc0 = __builtin_amdgcn_mfma_f32_16x16x32_bf16(al0, b0, acc0, 0, 0, 0);
        acc1 = __builtin_amdgcn_mfma_f32_16x16x32_bf16(al1, b1, acc1, 0, 0, 0);
        acc0 = __builtin_amdgcn_mfma_f32_16x16x32_bf16(ah0, b2, acc0, 0, 0, 0);
        acc1 = __builtin_amdgcn_mfma_f32_16x16x32_bf16(ah1, b3, acc1, 0, 0, 0);

        const float ek = ek_lds[t * 16 + col];
        const int cidx = t * 16 + col;
        #pragma unroll
        for (int r = 0; r < 4; ++r) {
            float d = ek - 2.f * (acc0[r] + acc1[r]);
            bool lt1 = d < d1[r];
            bool lt2 = d < d2[r];
            float nd2 = lt1 ? d1[r] : (lt2 ? d : d2[r]);
            int   ni2 = lt1 ? i1[r] : (lt2 ? cidx : i2[r]);
            d2[r] = nd2; i2[r] = ni2;
            d1[r] = lt1 ? d : d1[r];
            i1[r] = lt1 ? cidx : i1[r];
        }
        b0 = n0; b1 = n1; b2 = n2; b3 = n3;
    }

    // ---- butterfly-merge top-2 across the 16 col lanes ----
    #pragma unroll
    for (int m = 8; m >= 1; m >>= 1) {
        #pragma unroll
        for (int r = 0; r < 4; ++r) {
            float od1 = __shfl_xor(d1[r], m);
            int   oi1 = __shfl_xor(i1[r], m);
            float od2 = __shfl_xor(d2[r], m);
            int   oi2 = __shfl_xor(i2[r], m);
            bool aF = (d1[r] < od1) || (d1[r] == od1 && i1[r] < oi1);
            float n1 = aF ? d1[r] : od1;  int ni1 = aF ? i1[r] : oi1;
            float ca = aF ? od1 : d1[r];  int cia = aF ? oi1 : i1[r];
            float cb = aF ? d2[r] : od2;  int cib = aF ? i2[r] : oi2;
            bool bF = (cb < ca) || (cb == ca && cib < cia);
            float n2 = bF ? cb : ca;      int ni2 = bF ? cib : cia;
            d1[r] = n1; i1[r] = ni1; d2[r] = n2; i2[r] = ni2;
        }
    }
    if (col == 0) {
        #pragma unroll
        for (int r = 0; r < 4; ++r) {
            int lr = wave * 16 + quad * 4 + r;   // C layout: row = quad*4 + reg
            d1s[lr] = d1[r]; i1s[lr] = i1[r];
            d2s[lr] = d2[r]; i2s[lr] = i2[r];
        }
    }
    __syncthreads();

    // ---- wave 0: rescore near-ties exact; commit idx + hist + loss ----
    if (tid < ROWS_PB) {
        int am = i1s[tid];
        float dfin = d1s[tid];
        if (d2s[tid] - dfin < MARGIN) {
            int ia = i1s[tid], ib = i2s[tid];
            const float* xr = &lds_x[tid * XSTRIDE];
            float da, db;
            {
                const vf4* er = (const vf4*)(emb + ia * ND);
                float s0 = 0.f, s1 = 0.f, s2 = 0.f, s3 = 0.f;
                #pragma unroll
                for (int j = 0; j < 16; ++j) {
                    vf4 v = er[j];
                    s0 += xr[4 * j] * v.x; s1 += xr[4 * j + 1] * v.y;
                    s2 += xr[4 * j + 2] * v.z; s3 += xr[4 * j + 3] * v.w;
                }
                da = ek_lds[ia] - 2.f * ((s0 + s1) + (s2 + s3));
            }
            {
                const vf4* er = (const vf4*)(emb + ib * ND);
                float s0 = 0.f, s1 = 0.f, s2 = 0.f, s3 = 0.f;
                #pragma unroll
                for (int j = 0; j < 16; ++j) {
                    vf4 v = er[j];
                    s0 += xr[4 * j] * v.x; s1 += xr[4 * j + 1] * v.y;
                    s2 += xr[4 * j + 2] * v.z; s3 += xr[4 * j + 3] * v.w;
                }
                db = ek_lds[ib] - 2.f * ((s0 + s1) + (s2 + s3));
            }
            bool useB = (db < da) || (db == da && ib < ia);   // numpy tie-break
            am   = useB ? ib : ia;
            dfin = useB ? db : da;
        }
        idx_s[tid] = am;
        atomicAdd(&g_counts[am], 1);

        // loss partial: |x-e|^2 = xnorm + dfin
        float xn;
        {
            const float* xr = &lds_x[tid * XSTRIDE];
            float s0 = 0.f, s1 = 0.f, s2 = 0.f, s3 = 0.f;
            #pragma unroll
            for (int j = 0; j < 16; ++j) {
                s0 += xr[4 * j] * xr[4 * j];         s1 += xr[4 * j + 1] * xr[4 * j + 1];
                s2 += xr[4 * j + 2] * xr[4 * j + 2]; s3 += xr[4 * j + 3] * xr[4 * j + 3];
            }
            xn = (s0 + s1) + (s2 + s3);
        }
        float lossv = xn + dfin;
        #pragma unroll
        for (int off = 32; off >= 1; off >>= 1) lossv += __shfl_down(lossv, off);
        if (tid == 0) atomicAdd(g_loss, lossv);
    }
    __syncthreads();   // idx_s visible to all

    // ---- quantized gather LOADS first (registers) — latency hides under the
    //      enc store drain below; stores issued after the enc burst. ----
    float qv[16];
    {
        #pragma unroll
        for (int i = 0; i < 16; ++i) {
            int p = tid + i * BLOCK;
            qv[i] = emb[idx_s[p >> 6] * ND + (p & 63)];
        }
    }

    // ---- encodings: arithmetic one-hot, plain vf4 stores.
    //      Slice base byte addr ≡ 8 mod 16 -> vf2 head/tail + 8191 vf4. ----
    float* ebase = out + ENC_OFF + (size_t)blockIdx.x * (ROWS_PB * NK);
    if (tid == 0) {
        int a0 = idx_s[0];
        vf2 h; h.x = (a0 == 0) ? 1.f : 0.f; h.y = (a0 == 1) ? 1.f : 0.f;
        *(vf2*)ebase = h;
        int a63 = idx_s[63];
        vf2 tl; tl.x = (a63 == 510) ? 1.f : 0.f; tl.y = (a63 == 511) ? 1.f : 0.f;
        *(vf2*)(ebase + ROWS_PB * NK - 2) = tl;
    }
    {
        const int c0 = (2 + 4 * tid) & 511;    // column base, constant per thread
        const int rb = (2 + 4 * tid) >> 9;     // 0 or 1
        if (c0 != 510) {
            #pragma unroll
            for (int i = 0; i < 32; ++i) {
                int p = tid + i * BLOCK;
                if (p < 8191) {
                    int am = idx_s[rb + 2 * i];
                    vf4 v;
                    v.x = (am == c0)     ? 1.f : 0.f;
                    v.y = (am == c0 + 1) ? 1.f : 0.f;
                    v.z = (am == c0 + 2) ? 1.f : 0.f;
                    v.w = (am == c0 + 3) ? 1.f : 0.f;
                    *(vf4*)(ebase + 2 + 4 * (size_t)p) = v;
                }
            }
        } else {
            // tid 127 & 255: vf4 spans cols {510,511} of row r and {0,1} of r+1
            #pragma unroll
            for (int i = 0; i < 32; ++i) {
                int p = tid + i * BLOCK;
                if (p < 8191) {
                    int r0 = rb + 2 * i;
                    int am0 = idx_s[r0];
                    int am1 = idx_s[r0 + 1];
                    vf4 v;
                    v.x = (am0 == 510) ? 1.f : 0.f;
                    v.y = (am0 == 511) ? 1.f : 0.f;
                    v.z = (am1 == 0)   ? 1.f : 0.f;
                    v.w = (am1 == 1)   ? 1.f : 0.f;
                    *(vf4*)(ebase + 2 + 4 * (size_t)p) = v;
                }
            }
        }
    }

    // ---- quantized stores (loads already resolved above) ----
    {
        float* qout = out + Q_OFF + (size_t)blockIdx.x * (ROWS_PB * ND);
        #pragma unroll
        for (int i = 0; i < 16; ++i) {
            qout[tid + i * BLOCK] = qv[i];
        }
    }
}

__global__ __launch_bounds__(512) void vq_final(const int* __restrict__ g_counts,
                                                const float* __restrict__ g_loss,
                                                float* __restrict__ out) {
    __shared__ float red[8];
    int t = threadIdx.x;
    float p = (float)g_counts[t] * (1.0f / (float)NROWS);
    float h = p * logf(p + 1e-10f);
    #pragma unroll
    for (int off = 32; off >= 1; off >>= 1) h += __shfl_down(h, off);
    if ((t & 63) == 0) red[t >> 6] = h;
    __syncthreads();
    if (t == 0) {
        float s = 0.f;
        #pragma unroll
        for (int i = 0; i < 8; ++i) s += red[i];
        out[PERP_OFF] = expf(-s);
        out[0] = 0.25f * g_loss[0] / (float)(NROWS * ND);
    }
}

extern "C" void kernel_launch(void* const* d_in, const int* in_sizes, int n_in,
                              void* d_out, int out_size, void* d_ws, size_t ws_size,
                              hipStream_t stream) {
    const float* x   = (const float*)d_in[0];
    const float* emb = (const float*)d_in[1];
    float* out = (float*)d_out;

    int*          g_counts = (int*)d_ws;                           // 512 ints
    float*        g_loss   = (float*)((char*)d_ws + 2048);         // 1 float
    float*        eknorm   = (float*)((char*)d_ws + 4096);         // 512 floats
    unsigned int* efrag    = (unsigned int*)((char*)d_ws + 8192);  // 128 KB

    // ws re-poisoned to 0xAA before every launch — zero counts+loss.
    (void)hipMemsetAsync(d_ws, 0, 4096, stream);

    vq_prep<<<NTILES, 64, 0, stream>>>(emb, eknorm, efrag);
    vq_main<<<NBLOCKS, BLOCK, 0, stream>>>(x, emb, eknorm, efrag, out, g_counts, g_loss);
    vq_final<<<1, 512, 0, stream>>>(g_counts, g_loss, out);
}